// Round 1
// baseline (260.344 us; speedup 1.0000x reference)
//
#include <hip/hip_runtime.h>

#define N_PIX 16384   // 4 * 64 * 64

// ---------------------------------------------------------------------------
// Kernel 1: 3x3 SAME conv, 16 -> 8 channels. ang[oc*N_PIX + p] = y + bias.
// ---------------------------------------------------------------------------
__global__ __launch_bounds__(256) void conv_kernel(
    const float* __restrict__ x, const float* __restrict__ cw,
    const float* __restrict__ cb, float* __restrict__ ang) {
  int tid = blockIdx.x * blockDim.x + threadIdx.x;  // 131072 threads
  int oc = tid >> 14;
  int p  = tid & (N_PIX - 1);
  int b  = p >> 12;
  int h  = (p >> 6) & 63;
  int w  = p & 63;
  float acc = cb[oc];
  for (int ic = 0; ic < 16; ++ic) {
    const float* xp = x + ((b * 16 + ic) * 64) * 64;
    const float* wp = cw + (oc * 16 + ic) * 9;
#pragma unroll
    for (int kh = 0; kh < 3; ++kh) {
      int ih = h + kh - 1;
      if ((unsigned)ih < 64u) {
#pragma unroll
        for (int kw = 0; kw < 3; ++kw) {
          int iw = w + kw - 1;
          if ((unsigned)iw < 64u)
            acc = fmaf(xp[ih * 64 + iw], wp[kh * 3 + kw], acc);
        }
      }
    }
  }
  ang[oc * N_PIX + p] = acc;
}

// ---------------------------------------------------------------------------
// Kernel 2: precompute the 80 gate matrices (5 blocks x (8 u3 + 8 cu3)).
// Layout per gate (8 floats): u00r,u00i,u01r,u01i,u10r,u10i,u11r,u11i
// ---------------------------------------------------------------------------
__global__ void gates_kernel(const float* __restrict__ u3p,
                             const float* __restrict__ cu3p,
                             float* __restrict__ G) {
  int g = blockIdx.x * blockDim.x + threadIdx.x;
  if (g >= 80) return;
  int blk = g >> 4;
  int idx = g & 15;
  const float* src = (idx < 8) ? (u3p + (blk * 8 + idx) * 3)
                               : (cu3p + (blk * 8 + (idx - 8)) * 3);
  float th = src[0], ph = src[1], lam = src[2];
  float c = cosf(0.5f * th), s = sinf(0.5f * th);
  float cl = cosf(lam), sl = sinf(lam);
  float cp = cosf(ph), sp = sinf(ph);
  float cpl = cosf(ph + lam), spl = sinf(ph + lam);
  float* o = G + g * 8;
  o[0] = c;        o[1] = 0.0f;
  o[2] = -cl * s;  o[3] = -sl * s;
  o[4] = cp * s;   o[5] = sp * s;
  o[6] = cpl * c;  o[7] = spl * c;
}

// ---------------------------------------------------------------------------
// Quantum simulator: one pixel per wave64. amp index i = lane*4 + r.
// Wire w <-> bit (7-w) of i: wires 0..5 = lane bits 5..0, wire6 = r bit1,
// wire7 = r bit0.
// ---------------------------------------------------------------------------
__device__ __forceinline__ void cgate_cross(float ar[4], float ai[4],
    const float* __restrict__ u, int lane, int m, int ctrlmask) {
  const bool hi = (lane & m) != 0;
  const bool ctrl = ctrlmask ? ((lane & ctrlmask) != 0) : true;
  const float fr = hi ? u[6] : u[0];  // coeff of my amp
  const float fi = hi ? u[7] : u[1];
  const float gr = hi ? u[4] : u[2];  // coeff of partner amp
  const float gi = hi ? u[5] : u[3];
#pragma unroll
  for (int r = 0; r < 4; ++r) {
    float br = __shfl_xor(ar[r], m, 64);
    float bi = __shfl_xor(ai[r], m, 64);
    float nr = fr * ar[r] - fi * ai[r] + gr * br - gi * bi;
    float ni = fr * ai[r] + fi * ar[r] + gr * bi + gi * br;
    ar[r] = ctrl ? nr : ar[r];
    ai[r] = ctrl ? ni : ai[r];
  }
}

__device__ __forceinline__ void gate_intra(float ar[4], float ai[4],
    const float* __restrict__ u, int i0, int i1, bool ctrl) {
  float a0r = ar[i0], a0i = ai[i0], a1r = ar[i1], a1i = ai[i1];
  float n0r = u[0] * a0r - u[1] * a0i + u[2] * a1r - u[3] * a1i;
  float n0i = u[0] * a0i + u[1] * a0r + u[2] * a1i + u[3] * a1r;
  float n1r = u[4] * a0r - u[5] * a0i + u[6] * a1r - u[7] * a1i;
  float n1i = u[4] * a0i + u[5] * a0r + u[6] * a1i + u[7] * a1r;
  ar[i0] = ctrl ? n0r : a0r;  ai[i0] = ctrl ? n0i : a0i;
  ar[i1] = ctrl ? n1r : a1r;  ai[i1] = ctrl ? n1i : a1i;
}

// cu3 wire7: control = r bit0, target = lane bit5. Update r in {1,3} only.
__device__ __forceinline__ void cu3_w7(float ar[4], float ai[4],
    const float* __restrict__ u, int lane) {
  const bool hi = (lane & 32) != 0;
  const float fr = hi ? u[6] : u[0];
  const float fi = hi ? u[7] : u[1];
  const float gr = hi ? u[4] : u[2];
  const float gi = hi ? u[5] : u[3];
#pragma unroll
  for (int rr = 0; rr < 2; ++rr) {
    const int r = rr * 2 + 1;  // 1, 3
    float br = __shfl_xor(ar[r], 32, 64);
    float bi = __shfl_xor(ai[r], 32, 64);
    float nr = fr * ar[r] - fi * ai[r] + gr * br - gi * bi;
    float ni = fr * ai[r] + fi * ar[r] + gr * bi + gi * br;
    ar[r] = nr;  ai[r] = ni;
  }
}

// Hadamard on all 8 wires, unnormalized; rescale by 2^-4 at the end.
__device__ __forceinline__ void h_all(float ar[4], float ai[4], int lane) {
#pragma unroll
  for (int k = 0; k < 6; ++k) {
    int m = 1 << k;
    bool hi = (lane & m) != 0;
#pragma unroll
    for (int r = 0; r < 4; ++r) {
      float br = __shfl_xor(ar[r], m, 64);
      float bi = __shfl_xor(ai[r], m, 64);
      ar[r] = hi ? (br - ar[r]) : (ar[r] + br);
      ai[r] = hi ? (bi - ai[r]) : (ai[r] + bi);
    }
  }
  float t;
  t = ar[0]; ar[0] = t + ar[2]; ar[2] = t - ar[2];
  t = ai[0]; ai[0] = t + ai[2]; ai[2] = t - ai[2];
  t = ar[1]; ar[1] = t + ar[3]; ar[3] = t - ar[3];
  t = ai[1]; ai[1] = t + ai[3]; ai[3] = t - ai[3];
  t = ar[0]; ar[0] = t + ar[1]; ar[1] = t - ar[1];
  t = ai[0]; ai[0] = t + ai[1]; ai[1] = t - ai[1];
  t = ar[2]; ar[2] = t + ar[3]; ar[3] = t - ar[3];
  t = ai[2]; ai[2] = t + ai[3]; ai[3] = t - ai[3];
#pragma unroll
  for (int r = 0; r < 4; ++r) { ar[r] *= 0.0625f; ai[r] *= 0.0625f; }
}

// YROT = [[1,-i],[1,i]]/sqrt2 on all 8 wires, unnormalized; rescale 2^-4.
__device__ __forceinline__ void y_all(float ar[4], float ai[4], int lane) {
#pragma unroll
  for (int k = 0; k < 6; ++k) {
    int m = 1 << k;
    bool hi = (lane & m) != 0;
#pragma unroll
    for (int r = 0; r < 4; ++r) {
      float br = __shfl_xor(ar[r], m, 64);
      float bi = __shfl_xor(ai[r], m, 64);
      float nr = hi ? (br - ai[r]) : (ar[r] + bi);
      float ni = hi ? (bi + ar[r]) : (ai[r] - br);
      ar[r] = nr;  ai[r] = ni;
    }
  }
  float a0r, a0i, a1r, a1i;
  a0r = ar[0]; a0i = ai[0]; a1r = ar[2]; a1i = ai[2];
  ar[0] = a0r + a1i; ai[0] = a0i - a1r; ar[2] = a0r - a1i; ai[2] = a0i + a1r;
  a0r = ar[1]; a0i = ai[1]; a1r = ar[3]; a1i = ai[3];
  ar[1] = a0r + a1i; ai[1] = a0i - a1r; ar[3] = a0r - a1i; ai[3] = a0i + a1r;
  a0r = ar[0]; a0i = ai[0]; a1r = ar[1]; a1i = ai[1];
  ar[0] = a0r + a1i; ai[0] = a0i - a1r; ar[1] = a0r - a1i; ai[1] = a0i + a1r;
  a0r = ar[2]; a0i = ai[2]; a1r = ar[3]; a1i = ai[3];
  ar[2] = a0r + a1i; ai[2] = a0i - a1r; ar[3] = a0r - a1i; ai[3] = a0i + a1r;
#pragma unroll
  for (int r = 0; r < 4; ++r) { ar[r] *= 0.0625f; ai[r] *= 0.0625f; }
}

// <Z_w> for all 8 wires, broadcast to every lane.
__device__ __forceinline__ void measure8(const float ar[4], const float ai[4],
                                         int lane, float out[8]) {
  float p0 = ar[0] * ar[0] + ai[0] * ai[0];
  float p1 = ar[1] * ar[1] + ai[1] * ai[1];
  float p2 = ar[2] * ar[2] + ai[2] * ai[2];
  float p3 = ar[3] * ar[3] + ai[3] * ai[3];
  float s  = p0 + p1 + p2 + p3;
  float d1 = (p0 + p1) - (p2 + p3);  // wire 6 (r bit1)
  float d0 = (p0 - p1) + (p2 - p3);  // wire 7 (r bit0)
  // 64-point Walsh-Hadamard over lanes: lane j = sum_l (-1)^popc(j&l) s_l
  float a = s;
#pragma unroll
  for (int k = 0; k < 6; ++k) {
    int m = 1 << k;
    float t = __shfl_xor(a, m, 64);
    a = (lane & m) ? (t - a) : (a + t);
  }
  out[0] = __shfl(a, 32, 64);
  out[1] = __shfl(a, 16, 64);
  out[2] = __shfl(a, 8, 64);
  out[3] = __shfl(a, 4, 64);
  out[4] = __shfl(a, 2, 64);
  out[5] = __shfl(a, 1, 64);
  float b = d1;
#pragma unroll
  for (int k = 0; k < 6; ++k) b += __shfl_xor(b, 1 << k, 64);
  out[6] = b;
  float c = d0;
#pragma unroll
  for (int k = 0; k < 6; ++k) c += __shfl_xor(c, 1 << k, 64);
  out[7] = c;
}

__global__ __launch_bounds__(256) void qsim_kernel(
    const float* __restrict__ ang, const float* __restrict__ G,
    const float* __restrict__ fcw, const float* __restrict__ fcb,
    float* __restrict__ out) {
  const int lane = threadIdx.x & 63;
  const int p = (int)((blockIdx.x * (unsigned)blockDim.x + threadIdx.x) >> 6);

  // RY(theta)|0> product state
  float c[8], s[8];
#pragma unroll
  for (int w = 0; w < 8; ++w) {
    float a = 0.5f * ang[w * N_PIX + p];
    c[w] = cosf(a);
    s[w] = sinf(a);
  }
  float f = ((lane & 32) ? s[0] : c[0]);
  f *= ((lane & 16) ? s[1] : c[1]);
  f *= ((lane & 8) ? s[2] : c[2]);
  f *= ((lane & 4) ? s[3] : c[3]);
  f *= ((lane & 2) ? s[4] : c[4]);
  f *= ((lane & 1) ? s[5] : c[5]);
  float ar[4], ai[4];
  ar[0] = f * c[6] * c[7];
  ar[1] = f * c[6] * s[7];
  ar[2] = f * s[6] * c[7];
  ar[3] = f * s[6] * s[7];
  ai[0] = ai[1] = ai[2] = ai[3] = 0.0f;

  // 5 blocks: u3 on wires 0..7, then cu3 ring w -> (w+1)%8
  const float* g = G;
  for (int blk = 0; blk < 5; ++blk) {
    cgate_cross(ar, ai, g + 0,  lane, 32, 0);   // u3 wire 0
    cgate_cross(ar, ai, g + 8,  lane, 16, 0);   // wire 1
    cgate_cross(ar, ai, g + 16, lane, 8, 0);    // wire 2
    cgate_cross(ar, ai, g + 24, lane, 4, 0);    // wire 3
    cgate_cross(ar, ai, g + 32, lane, 2, 0);    // wire 4
    cgate_cross(ar, ai, g + 40, lane, 1, 0);    // wire 5
    gate_intra(ar, ai, g + 48, 0, 2, true);     // wire 6 (r bit1)
    gate_intra(ar, ai, g + 48, 1, 3, true);
    gate_intra(ar, ai, g + 56, 0, 1, true);     // wire 7 (r bit0)
    gate_intra(ar, ai, g + 56, 2, 3, true);
    const float* h = g + 64;
    cgate_cross(ar, ai, h + 0,  lane, 16, 32);  // cu3 0->1
    cgate_cross(ar, ai, h + 8,  lane, 8, 16);   // 1->2
    cgate_cross(ar, ai, h + 16, lane, 4, 8);    // 2->3
    cgate_cross(ar, ai, h + 24, lane, 2, 4);    // 3->4
    cgate_cross(ar, ai, h + 32, lane, 1, 2);    // 4->5
    gate_intra(ar, ai, h + 40, 0, 2, (lane & 1) != 0);  // 5->6
    gate_intra(ar, ai, h + 40, 1, 3, (lane & 1) != 0);
    gate_intra(ar, ai, h + 48, 2, 3, true);     // 6->7 (ctrl r bit1)
    cu3_w7(ar, ai, h + 56, lane);               // 7->0
    g += 128;
  }

  float mz[8], mx[8], my[8];
  measure8(ar, ai, lane, mz);
  h_all(ar, ai, lane);
  measure8(ar, ai, lane, mx);
  y_all(ar, ai, lane);
  measure8(ar, ai, lane, my);

  if (lane < 32) {
    const float* wr = fcw + lane * 24;
    float acc = fcb[lane];
#pragma unroll
    for (int j = 0; j < 8; ++j) acc = fmaf(mz[j], wr[j], acc);
#pragma unroll
    for (int j = 0; j < 8; ++j) acc = fmaf(mx[j], wr[8 + j], acc);
#pragma unroll
    for (int j = 0; j < 8; ++j) acc = fmaf(my[j], wr[16 + j], acc);
    // out[b, c, h, w] with c = lane
    out[(p >> 12) * 131072 + lane * 4096 + (p & 4095)] = acc;
  }
}

extern "C" void kernel_launch(void* const* d_in, const int* in_sizes, int n_in,
                              void* d_out, int out_size, void* d_ws, size_t ws_size,
                              hipStream_t stream) {
  const float* x      = (const float*)d_in[0];
  const float* conv_w = (const float*)d_in[1];
  const float* conv_b = (const float*)d_in[2];
  const float* u3p    = (const float*)d_in[3];
  const float* cu3p   = (const float*)d_in[4];
  const float* fcw    = (const float*)d_in[5];
  const float* fcb    = (const float*)d_in[6];
  float* out = (float*)d_out;

  float* ws  = (float*)d_ws;
  float* ang = ws;             // 8 * 16384 floats
  float* G   = ws + 8 * N_PIX; // 80 * 8 floats

  conv_kernel<<<512, 256, 0, stream>>>(x, conv_w, conv_b, ang);
  gates_kernel<<<1, 128, 0, stream>>>(u3p, cu3p, G);
  qsim_kernel<<<4096, 256, 0, stream>>>(ang, G, fcw, fcb, out);
}

// Round 2
// 209.085 us; speedup vs baseline: 1.2452x; 1.2452x over previous
//
#include <hip/hip_runtime.h>

#define N_PIX 16384   // 4 * 64 * 64

// ---------------------------------------------------------------------------
// Cross-lane butterfly helpers.
//   xor 1 : DPP quad_perm [1,0,3,2]  (VALU pipe, ~4 cyc)
//   xor 2 : DPP quad_perm [2,3,0,1]
//   xor 8 : DPP row_ror:8  ((l&15)+8 mod 16 == l^8)
//   xor 4 : ds_swizzle bit-mode (4<<10)|0x1F
//   xor 16: ds_swizzle bit-mode (16<<10)|0x1F
//   xor 32: ds_bpermute (bit-mode swizzle is 32-lane only)
// ---------------------------------------------------------------------------
template<int C>
__device__ __forceinline__ float dppmov(float x) {
  return __int_as_float(__builtin_amdgcn_update_dpp(0, __float_as_int(x), C, 0xF, 0xF, true));
}
template<int IMM>
__device__ __forceinline__ float dswz(float x) {
  return __int_as_float(__builtin_amdgcn_ds_swizzle(__float_as_int(x), IMM));
}
__device__ __forceinline__ float bperm(float x, int a32) {
  return __int_as_float(__builtin_amdgcn_ds_bpermute(a32, __float_as_int(x)));
}
template<int M>
__device__ __forceinline__ float bfly(float x, int a32) {
  if constexpr (M == 1)       return dppmov<0xB1>(x);
  else if constexpr (M == 2)  return dppmov<0x4E>(x);
  else if constexpr (M == 8)  return dppmov<0x128>(x);
  else if constexpr (M == 4)  return dswz<0x101F>(x);
  else if constexpr (M == 16) return dswz<0x401F>(x);
  else                        return bperm(x, a32);
}
__device__ __forceinline__ float rdlane(float x, int l) {
  return __int_as_float(__builtin_amdgcn_readlane(__float_as_int(x), l));
}
__device__ __forceinline__ float rdfirst(float x) {
  return __int_as_float(__builtin_amdgcn_readfirstlane(__float_as_int(x)));
}

// Two pixels per wave: states A and B. amp index i = lane*4 + r;
// wire w <-> bit (7-w): wires 0..5 = lane bits 5..0, wire6 = r bit1, wire7 = r bit0.
struct St { float r[4], i[4]; };

// Cross-lane gate on lane-mask M; CM = control lane-mask (0 = uncontrolled u3).
// Control folded into coefficients (identity on ctrl=0 lanes) -> no result cndmask.
template<int M, int CM>
__device__ __forceinline__ void cross2(St& A, St& B, const float* __restrict__ u,
                                       int lane, int a32) {
  const bool hi = (lane & M) != 0;
  float fr, fi, gr, gi;
  if constexpr (CM == 0) {
    fr = hi ? u[6] : u[0];  fi = hi ? u[7] : u[1];
    gr = hi ? u[4] : u[2];  gi = hi ? u[5] : u[3];
  } else {
    const bool ct = (lane & CM) != 0;
    fr = ct ? (hi ? u[6] : u[0]) : 1.0f;
    fi = ct ? (hi ? u[7] : u[1]) : 0.0f;
    gr = ct ? (hi ? u[4] : u[2]) : 0.0f;
    gi = ct ? (hi ? u[5] : u[3]) : 0.0f;
  }
  float pAr[4], pAi[4], pBr[4], pBi[4];
#pragma unroll
  for (int r = 0; r < 4; ++r) {
    pAr[r] = bfly<M>(A.r[r], a32);  pAi[r] = bfly<M>(A.i[r], a32);
    pBr[r] = bfly<M>(B.r[r], a32);  pBi[r] = bfly<M>(B.i[r], a32);
  }
#pragma unroll
  for (int r = 0; r < 4; ++r) {
    float nAr = fr*A.r[r] - fi*A.i[r] + gr*pAr[r] - gi*pAi[r];
    float nAi = fr*A.i[r] + fi*A.r[r] + gr*pAi[r] + gi*pAr[r];
    float nBr = fr*B.r[r] - fi*B.i[r] + gr*pBr[r] - gi*pBi[r];
    float nBi = fr*B.i[r] + fi*B.r[r] + gr*pBi[r] + gi*pBr[r];
    A.r[r]=nAr; A.i[r]=nAi; B.r[r]=nBr; B.i[r]=nBi;
  }
}

__device__ __forceinline__ void mix(float& x0r, float& x0i, float& x1r, float& x1i,
    float u0r, float u0i, float u1r, float u1i,
    float u2r, float u2i, float u3r, float u3i) {
  float n0r = u0r*x0r - u0i*x0i + u1r*x1r - u1i*x1i;
  float n0i = u0r*x0i + u0i*x0r + u1r*x1i + u1i*x1r;
  float n1r = u2r*x0r - u2i*x0i + u3r*x1r - u3i*x1i;
  float n1i = u2r*x0i + u2i*x0r + u3r*x1i + u3i*x1r;
  x0r=n0r; x0i=n0i; x1r=n1r; x1i=n1i;
}

// u3 on wire6 (reg bit1): pairs (0,2),(1,3)
__device__ __forceinline__ void intra62(St& A, St& B, const float* __restrict__ u) {
  mix(A.r[0],A.i[0],A.r[2],A.i[2],u[0],u[1],u[2],u[3],u[4],u[5],u[6],u[7]);
  mix(A.r[1],A.i[1],A.r[3],A.i[3],u[0],u[1],u[2],u[3],u[4],u[5],u[6],u[7]);
  mix(B.r[0],B.i[0],B.r[2],B.i[2],u[0],u[1],u[2],u[3],u[4],u[5],u[6],u[7]);
  mix(B.r[1],B.i[1],B.r[3],B.i[3],u[0],u[1],u[2],u[3],u[4],u[5],u[6],u[7]);
}
// u3 on wire7 (reg bit0): pairs (0,1),(2,3)
__device__ __forceinline__ void intra72(St& A, St& B, const float* __restrict__ u) {
  mix(A.r[0],A.i[0],A.r[1],A.i[1],u[0],u[1],u[2],u[3],u[4],u[5],u[6],u[7]);
  mix(A.r[2],A.i[2],A.r[3],A.i[3],u[0],u[1],u[2],u[3],u[4],u[5],u[6],u[7]);
  mix(B.r[0],B.i[0],B.r[1],B.i[1],u[0],u[1],u[2],u[3],u[4],u[5],u[6],u[7]);
  mix(B.r[2],B.i[2],B.r[3],B.i[3],u[0],u[1],u[2],u[3],u[4],u[5],u[6],u[7]);
}
// cu3 5->6: control lane bit0, target reg bit1
__device__ __forceinline__ void cu3_56(St& A, St& B, const float* __restrict__ u, int lane) {
  const bool ct = (lane & 1) != 0;
  float u0r = ct?u[0]:1.0f, u0i = ct?u[1]:0.0f, u1r = ct?u[2]:0.0f, u1i = ct?u[3]:0.0f;
  float u2r = ct?u[4]:0.0f, u2i = ct?u[5]:0.0f, u3r = ct?u[6]:1.0f, u3i = ct?u[7]:0.0f;
  mix(A.r[0],A.i[0],A.r[2],A.i[2],u0r,u0i,u1r,u1i,u2r,u2i,u3r,u3i);
  mix(A.r[1],A.i[1],A.r[3],A.i[3],u0r,u0i,u1r,u1i,u2r,u2i,u3r,u3i);
  mix(B.r[0],B.i[0],B.r[2],B.i[2],u0r,u0i,u1r,u1i,u2r,u2i,u3r,u3i);
  mix(B.r[1],B.i[1],B.r[3],B.i[3],u0r,u0i,u1r,u1i,u2r,u2i,u3r,u3i);
}
// cu3 6->7: control reg bit1, target reg bit0 -> pair (2,3) only
__device__ __forceinline__ void cu3_67(St& A, St& B, const float* __restrict__ u) {
  mix(A.r[2],A.i[2],A.r[3],A.i[3],u[0],u[1],u[2],u[3],u[4],u[5],u[6],u[7]);
  mix(B.r[2],B.i[2],B.r[3],B.i[3],u[0],u[1],u[2],u[3],u[4],u[5],u[6],u[7]);
}
// cu3 7->0: control reg bit0 (r in {1,3}), target lane bit 32
__device__ __forceinline__ void cu3_70(St& A, St& B, const float* __restrict__ u,
                                       int lane, int a32) {
  const bool hi = (lane & 32) != 0;
  float fr = hi?u[6]:u[0], fi = hi?u[7]:u[1];
  float gr = hi?u[4]:u[2], gi = hi?u[5]:u[3];
#pragma unroll
  for (int rr = 0; rr < 2; ++rr) {
    const int r = 2*rr + 1;
    float pAr = bperm(A.r[r],a32), pAi = bperm(A.i[r],a32);
    float pBr = bperm(B.r[r],a32), pBi = bperm(B.i[r],a32);
    float nAr = fr*A.r[r]-fi*A.i[r]+gr*pAr-gi*pAi;
    float nAi = fr*A.i[r]+fi*A.r[r]+gr*pAi+gi*pAr;
    float nBr = fr*B.r[r]-fi*B.i[r]+gr*pBr-gi*pBi;
    float nBi = fr*B.i[r]+fi*B.r[r]+gr*pBi+gi*pBr;
    A.r[r]=nAr; A.i[r]=nAi; B.r[r]=nBr; B.i[r]=nBi;
  }
}

// Unnormalized Hadamard / YROT cross-lane steps (scale folded into FC weights)
template<int M>
__device__ __forceinline__ void hstep2(St& A, St& B, int lane, int a32) {
  const bool hi = (lane & M) != 0;
#pragma unroll
  for (int r = 0; r < 4; ++r) {
    float pAr=bfly<M>(A.r[r],a32), pAi=bfly<M>(A.i[r],a32);
    float pBr=bfly<M>(B.r[r],a32), pBi=bfly<M>(B.i[r],a32);
    A.r[r] = hi ? pAr-A.r[r] : A.r[r]+pAr;
    A.i[r] = hi ? pAi-A.i[r] : A.i[r]+pAi;
    B.r[r] = hi ? pBr-B.r[r] : B.r[r]+pBr;
    B.i[r] = hi ? pBi-B.i[r] : B.i[r]+pBi;
  }
}
template<int M>
__device__ __forceinline__ void ystep2(St& A, St& B, int lane, int a32) {
  const bool hi = (lane & M) != 0;
#pragma unroll
  for (int r = 0; r < 4; ++r) {
    float pAr=bfly<M>(A.r[r],a32), pAi=bfly<M>(A.i[r],a32);
    float pBr=bfly<M>(B.r[r],a32), pBi=bfly<M>(B.i[r],a32);
    float oAr=A.r[r], oAi=A.i[r], oBr=B.r[r], oBi=B.i[r];
    A.r[r] = hi ? pAr-oAi : oAr+pAi;
    A.i[r] = hi ? pAi+oAr : oAi-pAr;
    B.r[r] = hi ? pBr-oBi : oBr+pBi;
    B.i[r] = hi ? pBi+oBr : oBi-pBr;
  }
}
__device__ __forceinline__ void hpair(float& x0, float& x1){ float t=x0; x0=t+x1; x1=t-x1; }
__device__ __forceinline__ void h_intra(St& S){
  hpair(S.r[0],S.r[2]); hpair(S.i[0],S.i[2]); hpair(S.r[1],S.r[3]); hpair(S.i[1],S.i[3]);
  hpair(S.r[0],S.r[1]); hpair(S.i[0],S.i[1]); hpair(S.r[2],S.r[3]); hpair(S.i[2],S.i[3]);
}
__device__ __forceinline__ void ymix(float& x0r,float& x0i,float& x1r,float& x1i){
  float a0r=x0r,a0i=x0i,a1r=x1r,a1i=x1i;
  x0r=a0r+a1i; x0i=a0i-a1r; x1r=a0r-a1i; x1i=a0i+a1r;
}
__device__ __forceinline__ void y_intra(St& S){
  ymix(S.r[0],S.i[0],S.r[2],S.i[2]); ymix(S.r[1],S.i[1],S.r[3],S.i[3]);
  ymix(S.r[0],S.i[0],S.r[1],S.i[1]); ymix(S.r[2],S.i[2],S.r[3],S.i[3]);
}

// <Z_w> for both pixels; results come back wave-uniform (SGPRs via readlane).
__device__ __forceinline__ void measure2(const St& A, const St& B, int lane, int a32,
                                         float* mA, float* mB) {
  float pA[4], pB[4];
#pragma unroll
  for (int r = 0; r < 4; ++r) {
    pA[r] = A.r[r]*A.r[r] + A.i[r]*A.i[r];
    pB[r] = B.r[r]*B.r[r] + B.i[r]*B.i[r];
  }
  float aA = pA[0]+pA[1]+pA[2]+pA[3];
  float aB = pB[0]+pB[1]+pB[2]+pB[3];
  float d1A = (pA[0]+pA[1])-(pA[2]+pA[3]);
  float d1B = (pB[0]+pB[1])-(pB[2]+pB[3]);
  float d0A = (pA[0]-pA[1])+(pA[2]-pA[3]);
  float d0B = (pB[0]-pB[1])+(pB[2]-pB[3]);
  float t;
  t = bfly<1>(aA,a32);  aA = (lane&1)  ? t-aA : aA+t;
  t = bfly<1>(aB,a32);  aB = (lane&1)  ? t-aB : aB+t;
  t = bfly<2>(aA,a32);  aA = (lane&2)  ? t-aA : aA+t;
  t = bfly<2>(aB,a32);  aB = (lane&2)  ? t-aB : aB+t;
  t = bfly<4>(aA,a32);  aA = (lane&4)  ? t-aA : aA+t;
  t = bfly<4>(aB,a32);  aB = (lane&4)  ? t-aB : aB+t;
  t = bfly<8>(aA,a32);  aA = (lane&8)  ? t-aA : aA+t;
  t = bfly<8>(aB,a32);  aB = (lane&8)  ? t-aB : aB+t;
  t = bfly<16>(aA,a32); aA = (lane&16) ? t-aA : aA+t;
  t = bfly<16>(aB,a32); aB = (lane&16) ? t-aB : aB+t;
  t = bfly<32>(aA,a32); aA = (lane&32) ? t-aA : aA+t;
  t = bfly<32>(aB,a32); aB = (lane&32) ? t-aB : aB+t;
  mA[0]=rdlane(aA,32); mA[1]=rdlane(aA,16); mA[2]=rdlane(aA,8);
  mA[3]=rdlane(aA,4);  mA[4]=rdlane(aA,2);  mA[5]=rdlane(aA,1);
  mB[0]=rdlane(aB,32); mB[1]=rdlane(aB,16); mB[2]=rdlane(aB,8);
  mB[3]=rdlane(aB,4);  mB[4]=rdlane(aB,2);  mB[5]=rdlane(aB,1);
  d1A += bfly<1>(d1A,a32);  d1B += bfly<1>(d1B,a32);
  d0A += bfly<1>(d0A,a32);  d0B += bfly<1>(d0B,a32);
  d1A += bfly<2>(d1A,a32);  d1B += bfly<2>(d1B,a32);
  d0A += bfly<2>(d0A,a32);  d0B += bfly<2>(d0B,a32);
  d1A += bfly<4>(d1A,a32);  d1B += bfly<4>(d1B,a32);
  d0A += bfly<4>(d0A,a32);  d0B += bfly<4>(d0B,a32);
  d1A += bfly<8>(d1A,a32);  d1B += bfly<8>(d1B,a32);
  d0A += bfly<8>(d0A,a32);  d0B += bfly<8>(d0B,a32);
  d1A += bfly<16>(d1A,a32); d1B += bfly<16>(d1B,a32);
  d0A += bfly<16>(d0A,a32); d0B += bfly<16>(d0B,a32);
  d1A += bfly<32>(d1A,a32); d1B += bfly<32>(d1B,a32);
  d0A += bfly<32>(d0A,a32); d0B += bfly<32>(d0B,a32);
  mA[6]=rdfirst(d1A); mA[7]=rdfirst(d0A);
  mB[6]=rdfirst(d1B); mB[7]=rdfirst(d0B);
}

// ---------------------------------------------------------------------------
// Conv + gate/FC-table prep fused in one launch. Blocks 0..511: conv.
// Block 512: 80 gate matrices + pre-scaled FC weight copy.
// ---------------------------------------------------------------------------
__global__ __launch_bounds__(256) void conv_prep_kernel(
    const float* __restrict__ x, const float* __restrict__ cw,
    const float* __restrict__ cb, const float* __restrict__ u3p,
    const float* __restrict__ cu3p, const float* __restrict__ fcw,
    const float* __restrict__ fcb, float* __restrict__ ang,
    float* __restrict__ G, float* __restrict__ FCW, float* __restrict__ FCB) {
  if (blockIdx.x == 512) {
    int t = threadIdx.x;
    if (t < 80) {
      int blk = t >> 4, idx = t & 15;
      const float* src = (idx < 8) ? (u3p + (blk * 8 + idx) * 3)
                                   : (cu3p + (blk * 8 + (idx - 8)) * 3);
      float th = src[0], ph = src[1], lam = src[2];
      float c = cosf(0.5f * th), s = sinf(0.5f * th);
      float cl = cosf(lam), sl = sinf(lam);
      float cp = cosf(ph), sp = sinf(ph);
      float cpl = cosf(ph + lam), spl = sinf(ph + lam);
      float* o = G + t * 8;
      o[0] = c;        o[1] = 0.0f;
      o[2] = -cl * s;  o[3] = -sl * s;
      o[4] = cp * s;   o[5] = sp * s;
      o[6] = cpl * c;  o[7] = spl * c;
    }
    for (int i = t; i < 768; i += 256) {
      int col = i % 24;
      float sc = col < 8 ? 1.0f : (col < 16 ? (1.0f/256.0f) : (1.0f/65536.0f));
      FCW[i] = fcw[i] * sc;
    }
    if (t < 32) FCB[t] = fcb[t];
    return;
  }
  int tid = blockIdx.x * blockDim.x + threadIdx.x;
  int oc = tid >> 14;
  int p  = tid & (N_PIX - 1);
  int b  = p >> 12;
  int h  = (p >> 6) & 63;
  int w  = p & 63;
  float acc = cb[oc];
  for (int ic = 0; ic < 16; ++ic) {
    const float* xp = x + ((b * 16 + ic) * 64) * 64;
    const float* wp = cw + (oc * 16 + ic) * 9;
#pragma unroll
    for (int kh = 0; kh < 3; ++kh) {
      int ih = h + kh - 1;
      if ((unsigned)ih < 64u) {
#pragma unroll
        for (int kw = 0; kw < 3; ++kw) {
          int iw = w + kw - 1;
          if ((unsigned)iw < 64u)
            acc = fmaf(xp[ih * 64 + iw], wp[kh * 3 + kw], acc);
        }
      }
    }
  }
  ang[oc * N_PIX + p] = acc;
}

// ---------------------------------------------------------------------------
// Quantum simulator: 2 pixels per wave64, interleaved for ILP.
// ---------------------------------------------------------------------------
__global__ __launch_bounds__(256) void qsim_kernel(
    const float* __restrict__ ang, const float* __restrict__ G,
    const float* __restrict__ FCW, const float* __restrict__ FCB,
    float* __restrict__ out) {
  const int lane = threadIdx.x & 63;
  const int a32 = ((lane ^ 32) << 2);
  const int wid = __builtin_amdgcn_readfirstlane(
      (int)((blockIdx.x * blockDim.x + threadIdx.x) >> 6));
  const int p0 = wid * 2, p1 = p0 + 1;

  float cA[8], sA[8], cB[8], sB[8];
#pragma unroll
  for (int w = 0; w < 8; ++w) {
    float aa = 0.5f * ang[w * N_PIX + p0];
    float ab = 0.5f * ang[w * N_PIX + p1];
    __sincosf(aa, &sA[w], &cA[w]);
    __sincosf(ab, &sB[w], &cB[w]);
  }
  St A, B;
  {
    float fA = ((lane & 32) ? sA[0] : cA[0]) * ((lane & 16) ? sA[1] : cA[1]);
    fA *= ((lane & 8) ? sA[2] : cA[2]);
    fA *= ((lane & 4) ? sA[3] : cA[3]);
    fA *= ((lane & 2) ? sA[4] : cA[4]);
    fA *= ((lane & 1) ? sA[5] : cA[5]);
    A.r[0] = fA * (cA[6]*cA[7]); A.r[1] = fA * (cA[6]*sA[7]);
    A.r[2] = fA * (sA[6]*cA[7]); A.r[3] = fA * (sA[6]*sA[7]);
    A.i[0]=A.i[1]=A.i[2]=A.i[3]=0.0f;
    float fB = ((lane & 32) ? sB[0] : cB[0]) * ((lane & 16) ? sB[1] : cB[1]);
    fB *= ((lane & 8) ? sB[2] : cB[2]);
    fB *= ((lane & 4) ? sB[3] : cB[3]);
    fB *= ((lane & 2) ? sB[4] : cB[4]);
    fB *= ((lane & 1) ? sB[5] : cB[5]);
    B.r[0] = fB * (cB[6]*cB[7]); B.r[1] = fB * (cB[6]*sB[7]);
    B.r[2] = fB * (sB[6]*cB[7]); B.r[3] = fB * (sB[6]*sB[7]);
    B.i[0]=B.i[1]=B.i[2]=B.i[3]=0.0f;
  }

  const float* g = G;
  for (int blk = 0; blk < 5; ++blk) {
    cross2<32,0>(A,B,g+0, lane,a32);
    cross2<16,0>(A,B,g+8, lane,a32);
    cross2<8,0> (A,B,g+16,lane,a32);
    cross2<4,0> (A,B,g+24,lane,a32);
    cross2<2,0> (A,B,g+32,lane,a32);
    cross2<1,0> (A,B,g+40,lane,a32);
    intra62(A,B,g+48);
    intra72(A,B,g+56);
    const float* h = g + 64;
    cross2<16,32>(A,B,h+0, lane,a32);
    cross2<8,16> (A,B,h+8, lane,a32);
    cross2<4,8>  (A,B,h+16,lane,a32);
    cross2<2,4>  (A,B,h+24,lane,a32);
    cross2<1,2>  (A,B,h+32,lane,a32);
    cu3_56(A,B,h+40,lane);
    cu3_67(A,B,h+48);
    cu3_70(A,B,h+56,lane,a32);
    g += 128;
  }

  float mzA[8],mzB[8],mxA[8],mxB[8],myA[8],myB[8];
  measure2(A,B,lane,a32,mzA,mzB);
  hstep2<1>(A,B,lane,a32); hstep2<2>(A,B,lane,a32); hstep2<4>(A,B,lane,a32);
  hstep2<8>(A,B,lane,a32); hstep2<16>(A,B,lane,a32); hstep2<32>(A,B,lane,a32);
  h_intra(A); h_intra(B);
  measure2(A,B,lane,a32,mxA,mxB);
  ystep2<1>(A,B,lane,a32); ystep2<2>(A,B,lane,a32); ystep2<4>(A,B,lane,a32);
  ystep2<8>(A,B,lane,a32); ystep2<16>(A,B,lane,a32); ystep2<32>(A,B,lane,a32);
  y_intra(A); y_intra(B);
  measure2(A,B,lane,a32,myA,myB);

  // FC: lanes 0-31 -> pixel p0 channel lane; lanes 32-63 -> pixel p1.
  const bool selA = lane < 32;
  const int c = lane & 31;
  float wv[24];
  const float4* w4 = reinterpret_cast<const float4*>(FCW + c * 24);
#pragma unroll
  for (int q = 0; q < 6; ++q) {
    float4 t = w4[q];
    wv[q*4+0]=t.x; wv[q*4+1]=t.y; wv[q*4+2]=t.z; wv[q*4+3]=t.w;
  }
  float acc = FCB[c];
#pragma unroll
  for (int j = 0; j < 8; ++j) acc = fmaf(selA ? mzA[j] : mzB[j], wv[j], acc);
#pragma unroll
  for (int j = 0; j < 8; ++j) acc = fmaf(selA ? mxA[j] : mxB[j], wv[8+j], acc);
#pragma unroll
  for (int j = 0; j < 8; ++j) acc = fmaf(selA ? myA[j] : myB[j], wv[16+j], acc);
  int p = selA ? p0 : p1;
  out[(p >> 12) * 131072 + c * 4096 + (p & 4095)] = acc;
}

extern "C" void kernel_launch(void* const* d_in, const int* in_sizes, int n_in,
                              void* d_out, int out_size, void* d_ws, size_t ws_size,
                              hipStream_t stream) {
  const float* x      = (const float*)d_in[0];
  const float* conv_w = (const float*)d_in[1];
  const float* conv_b = (const float*)d_in[2];
  const float* u3p    = (const float*)d_in[3];
  const float* cu3p   = (const float*)d_in[4];
  const float* fcw    = (const float*)d_in[5];
  const float* fcb    = (const float*)d_in[6];
  float* out = (float*)d_out;

  float* ws  = (float*)d_ws;
  float* ang = ws;               // 8 * 16384
  float* G   = ws + 8 * N_PIX;   // 640
  float* FCW = G + 640;          // 768 (pre-scaled: cols 8-15 /256, 16-23 /65536)
  float* FCB = FCW + 768;        // 32

  conv_prep_kernel<<<513, 256, 0, stream>>>(x, conv_w, conv_b, u3p, cu3p,
                                            fcw, fcb, ang, G, FCW, FCB);
  qsim_kernel<<<2048, 256, 0, stream>>>(ang, G, FCW, FCB, out);
}

// Round 3
// 141.976 us; speedup vs baseline: 1.8337x; 1.4727x over previous
//
#include <hip/hip_runtime.h>

#define N_PIX 16384   // 4 * 64 * 64

typedef float v2f __attribute__((ext_vector_type(2)));

// ---------------------------------------------------------------------------
// Cross-lane butterfly helpers (see round-2: DPP for 1/2/8, swizzle 4/16,
// bpermute for 32).
// ---------------------------------------------------------------------------
template<int C>
__device__ __forceinline__ float dppmov(float x) {
  return __int_as_float(__builtin_amdgcn_update_dpp(0, __float_as_int(x), C, 0xF, 0xF, true));
}
template<int IMM>
__device__ __forceinline__ float dswz(float x) {
  return __int_as_float(__builtin_amdgcn_ds_swizzle(__float_as_int(x), IMM));
}
__device__ __forceinline__ float bperm(float x, int a32) {
  return __int_as_float(__builtin_amdgcn_ds_bpermute(a32, __float_as_int(x)));
}
template<int M>
__device__ __forceinline__ float bfly(float x, int a32) {
  if constexpr (M == 1)       return dppmov<0xB1>(x);
  else if constexpr (M == 2)  return dppmov<0x4E>(x);
  else if constexpr (M == 8)  return dppmov<0x128>(x);
  else if constexpr (M == 4)  return dswz<0x101F>(x);
  else if constexpr (M == 16) return dswz<0x401F>(x);
  else                        return bperm(x, a32);
}
template<int M>
__device__ __forceinline__ v2f bfly2(v2f v, int a32) {
  v2f o; o.x = bfly<M>(v.x, a32); o.y = bfly<M>(v.y, a32); return o;
}
__device__ __forceinline__ float rdlane(float x, int l) {
  return __int_as_float(__builtin_amdgcn_readlane(__float_as_int(x), l));
}
__device__ __forceinline__ float rdfirst(float x) {
  return __int_as_float(__builtin_amdgcn_readfirstlane(__float_as_int(x)));
}
__device__ __forceinline__ v2f sp(float s) { v2f v; v.x = s; v.y = s; return v; }
__device__ __forceinline__ v2f vfma(v2f a, v2f b, v2f c) {
  return __builtin_elementwise_fma(a, b, c);
}

// ---------------------------------------------------------------------------
// State: 2 pixels per wave packed in v2f (.x = pixel A, .y = pixel B).
// amp index i = lane*4 + r. wire w<=5 <-> lane mask 32>>w; wire6 = r bit1;
// wire7 = r bit0.
// ---------------------------------------------------------------------------

// Cross-lane gate, target lane-mask M. CM==0: single matrix g[0..7].
// CM!=0: two matrices g[0..7]=M0 (ctrl=0), g[8..15]=M1 (ctrl=1).
template<int M, int CM>
__device__ __forceinline__ void crossg(v2f Sr[4], v2f Si[4],
    const float* __restrict__ g, int lane, int a32) {
  const bool hi = (lane & M) != 0;
  float fr, fi, gr, gi;
  if constexpr (CM == 0) {
    fr = hi ? g[6] : g[0]; fi = hi ? g[7] : g[1];
    gr = hi ? g[4] : g[2]; gi = hi ? g[5] : g[3];
  } else {
    const bool ct = (lane & CM) != 0;
    float f0r = hi ? g[6]  : g[0],  f0i = hi ? g[7]  : g[1];
    float g0r = hi ? g[4]  : g[2],  g0i = hi ? g[5]  : g[3];
    float f1r = hi ? g[14] : g[8],  f1i = hi ? g[15] : g[9];
    float g1r = hi ? g[12] : g[10], g1i = hi ? g[13] : g[11];
    fr = ct ? f1r : f0r; fi = ct ? f1i : f0i;
    gr = ct ? g1r : g0r; gi = ct ? g1i : g0i;
  }
  v2f vfr = sp(fr), vfi = sp(fi), vgr = sp(gr), vgi = sp(gi);
  v2f vfiN = sp(-fi), vgiN = sp(-gi);
#pragma unroll
  for (int r = 0; r < 4; ++r) {
    v2f pR = bfly2<M>(Sr[r], a32);
    v2f pI = bfly2<M>(Si[r], a32);
    v2f nR = vfma(vgiN, pI, vfma(vgr, pR, vfma(vfiN, Si[r], vfr * Sr[r])));
    v2f nI = vfma(vgi,  pR, vfma(vgr, pI, vfma(vfi,  Sr[r], vfr * Si[r])));
    Sr[r] = nR; Si[r] = nI;
  }
}

// 2x2 on an intra-reg pair with per-lane scalar coefficients.
__device__ __forceinline__ void mixP(v2f& x0r, v2f& x0i, v2f& x1r, v2f& x1i,
    float m0r, float m0i, float m1r, float m1i,
    float m2r, float m2i, float m3r, float m3i) {
  v2f n0r = vfma(sp(-m1i), x1i, vfma(sp(m1r), x1r, vfma(sp(-m0i), x0i, sp(m0r) * x0r)));
  v2f n0i = vfma(sp( m1i), x1r, vfma(sp(m1r), x1i, vfma(sp( m0i), x0r, sp(m0r) * x0i)));
  v2f n1r = vfma(sp(-m3i), x1i, vfma(sp(m3r), x1r, vfma(sp(-m2i), x0i, sp(m2r) * x0r)));
  v2f n1i = vfma(sp( m3i), x1r, vfma(sp(m3r), x1i, vfma(sp( m2i), x0r, sp(m2r) * x0i)));
  x0r = n0r; x0i = n0i; x1r = n1r; x1i = n1i;
}

// F6: target reg bit1 (pairs (0,2),(1,3)), ctrl lane bit0 selects M0/M1.
__device__ __forceinline__ void f6(v2f Sr[4], v2f Si[4],
    const float* __restrict__ g, int lane) {
  const bool ct = (lane & 1) != 0;
  float m[8];
#pragma unroll
  for (int j = 0; j < 8; ++j) m[j] = ct ? g[8 + j] : g[j];
  mixP(Sr[0], Si[0], Sr[2], Si[2], m[0],m[1],m[2],m[3],m[4],m[5],m[6],m[7]);
  mixP(Sr[1], Si[1], Sr[3], Si[3], m[0],m[1],m[2],m[3],m[4],m[5],m[6],m[7]);
}

// F7: target reg bit0; pair (0,1) uses M0, pair (2,3) uses M1 (ctrl = reg bit1).
__device__ __forceinline__ void f7(v2f Sr[4], v2f Si[4],
    const float* __restrict__ g) {
  mixP(Sr[0], Si[0], Sr[1], Si[1], g[0],g[1],g[2],g[3],g[4],g[5],g[6],g[7]);
  mixP(Sr[2], Si[2], Sr[3], Si[3], g[8],g[9],g[10],g[11],g[12],g[13],g[14],g[15]);
}

// F8': target lane mask 32; even regs use M0, odd regs use M1 (ctrl = reg bit0).
__device__ __forceinline__ void f8p(v2f Sr[4], v2f Si[4],
    const float* __restrict__ g, int lane, int a32) {
  const bool hi = (lane & 32) != 0;
  float fr[2], fi[2], gr[2], gi[2];
  fr[0] = hi ? g[6]  : g[0];  fi[0] = hi ? g[7]  : g[1];
  gr[0] = hi ? g[4]  : g[2];  gi[0] = hi ? g[5]  : g[3];
  fr[1] = hi ? g[14] : g[8];  fi[1] = hi ? g[15] : g[9];
  gr[1] = hi ? g[12] : g[10]; gi[1] = hi ? g[13] : g[11];
#pragma unroll
  for (int r = 0; r < 4; ++r) {
    const int m = r & 1;
    v2f pR = bfly2<32>(Sr[r], a32);
    v2f pI = bfly2<32>(Si[r], a32);
    v2f nR = vfma(sp(-gi[m]), pI, vfma(sp(gr[m]), pR, vfma(sp(-fi[m]), Si[r], sp(fr[m]) * Sr[r])));
    v2f nI = vfma(sp( gi[m]), pR, vfma(sp(gr[m]), pI, vfma(sp( fi[m]), Sr[r], sp(fr[m]) * Si[r])));
    Sr[r] = nR; Si[r] = nI;
  }
}

// F8 final: cu3(7->0) standalone: only odd regs, target mask 32.
__device__ __forceinline__ void f8(v2f Sr[4], v2f Si[4],
    const float* __restrict__ g, int lane, int a32) {
  const bool hi = (lane & 32) != 0;
  float fr = hi ? g[6] : g[0], fi = hi ? g[7] : g[1];
  float gr = hi ? g[4] : g[2], gi = hi ? g[5] : g[3];
#pragma unroll
  for (int rr = 0; rr < 2; ++rr) {
    const int r = 2 * rr + 1;
    v2f pR = bfly2<32>(Sr[r], a32);
    v2f pI = bfly2<32>(Si[r], a32);
    v2f nR = vfma(sp(-gi), pI, vfma(sp(gr), pR, vfma(sp(-fi), Si[r], sp(fr) * Sr[r])));
    v2f nI = vfma(sp( gi), pR, vfma(sp(gr), pI, vfma(sp( fi), Sr[r], sp(fr) * Si[r])));
    Sr[r] = nR; Si[r] = nI;
  }
}

// Unnormalized Hadamard cross step: a = sgn*a + partner.
template<int M>
__device__ __forceinline__ void hstepP(v2f Sr[4], v2f Si[4], v2f sgn, int a32) {
#pragma unroll
  for (int r = 0; r < 4; ++r) {
    v2f pR = bfly2<M>(Sr[r], a32);
    v2f pI = bfly2<M>(Si[r], a32);
    Sr[r] = vfma(sgn, Sr[r], pR);
    Si[r] = vfma(sgn, Si[r], pI);
  }
}
__device__ __forceinline__ void hp(v2f& a, v2f& b) { v2f t = a; a = t + b; b = t - b; }
__device__ __forceinline__ void h_intraP(v2f Sr[4], v2f Si[4]) {
  hp(Sr[0], Sr[2]); hp(Si[0], Si[2]); hp(Sr[1], Sr[3]); hp(Si[1], Si[3]);
  hp(Sr[0], Sr[1]); hp(Si[0], Si[1]); hp(Sr[2], Sr[3]); hp(Si[2], Si[3]);
}

// diag(1,-i) on every wire: amp i *= (-i)^popc(i).
__device__ __forceinline__ void phaseY(v2f Sr[4], v2f Si[4], int lane) {
  const int pl = __popc(lane);
#pragma unroll
  for (int r = 0; r < 4; ++r) {
    const int pcr = (r == 0) ? 0 : ((r == 3) ? 2 : 1);
    const int q = (pl + pcr) & 3;
    const bool b0 = (q & 1) != 0;
    const bool b1 = (q & 2) != 0;
    const float sR = b1 ? -1.0f : 1.0f;
    const float sI = (b0 != b1) ? -1.0f : 1.0f;
    v2f Rs = b0 ? Si[r] : Sr[r];
    v2f Is = b0 ? Sr[r] : Si[r];
    Sr[r] = sp(sR) * Rs;
    Si[r] = sp(sI) * Is;
  }
}

// <Z_w> for both packed pixels; results wave-uniform via readlane.
__device__ __forceinline__ void measureP(const v2f Sr[4], const v2f Si[4],
    int lane, int a32, const float* sgv, float* mA, float* mB) {
  v2f P[4];
#pragma unroll
  for (int r = 0; r < 4; ++r) P[r] = vfma(Si[r], Si[r], Sr[r] * Sr[r]);
  v2f t01 = P[0] + P[1], t23 = P[2] + P[3];
  v2f a  = t01 + t23;
  v2f d1 = t01 - t23;                       // wire 6
  v2f d0 = (P[0] - P[1]) + (P[2] - P[3]);   // wire 7
  a = vfma(sp(sgv[0]), a, bfly2<1>(a, a32));
  a = vfma(sp(sgv[1]), a, bfly2<2>(a, a32));
  a = vfma(sp(sgv[2]), a, bfly2<4>(a, a32));
  a = vfma(sp(sgv[3]), a, bfly2<8>(a, a32));
  a = vfma(sp(sgv[4]), a, bfly2<16>(a, a32));
  a = vfma(sp(sgv[5]), a, bfly2<32>(a, a32));
  mA[0] = rdlane(a.x, 32); mA[1] = rdlane(a.x, 16); mA[2] = rdlane(a.x, 8);
  mA[3] = rdlane(a.x, 4);  mA[4] = rdlane(a.x, 2);  mA[5] = rdlane(a.x, 1);
  mB[0] = rdlane(a.y, 32); mB[1] = rdlane(a.y, 16); mB[2] = rdlane(a.y, 8);
  mB[3] = rdlane(a.y, 4);  mB[4] = rdlane(a.y, 2);  mB[5] = rdlane(a.y, 1);
  d1 = d1 + bfly2<1>(d1, a32);  d0 = d0 + bfly2<1>(d0, a32);
  d1 = d1 + bfly2<2>(d1, a32);  d0 = d0 + bfly2<2>(d0, a32);
  d1 = d1 + bfly2<4>(d1, a32);  d0 = d0 + bfly2<4>(d0, a32);
  d1 = d1 + bfly2<8>(d1, a32);  d0 = d0 + bfly2<8>(d0, a32);
  d1 = d1 + bfly2<16>(d1, a32); d0 = d0 + bfly2<16>(d0, a32);
  d1 = d1 + bfly2<32>(d1, a32); d0 = d0 + bfly2<32>(d0, a32);
  mA[6] = rdfirst(d1.x); mA[7] = rdfirst(d0.x);
  mB[6] = rdfirst(d1.y); mB[7] = rdfirst(d0.y);
}

// ---------------------------------------------------------------------------
// Prep helpers (complex 2x2 product, row-major r,i interleaved).
// ---------------------------------------------------------------------------
__device__ __forceinline__ void mm2(const float* A, const float* B, float* D) {
  D[0] = A[0]*B[0] - A[1]*B[1] + A[2]*B[4] - A[3]*B[5];
  D[1] = A[0]*B[1] + A[1]*B[0] + A[2]*B[5] + A[3]*B[4];
  D[2] = A[0]*B[2] - A[1]*B[3] + A[2]*B[6] - A[3]*B[7];
  D[3] = A[0]*B[3] + A[1]*B[2] + A[2]*B[7] + A[3]*B[6];
  D[4] = A[4]*B[0] - A[5]*B[1] + A[6]*B[4] - A[7]*B[5];
  D[5] = A[4]*B[1] + A[5]*B[0] + A[6]*B[5] + A[7]*B[4];
  D[6] = A[4]*B[2] - A[5]*B[3] + A[6]*B[6] - A[7]*B[7];
  D[7] = A[4]*B[3] + A[5]*B[2] + A[6]*B[7] + A[7]*B[6];
}
__device__ __forceinline__ void u3fill(const float* src, float* o) {
  float th = src[0], ph = src[1], lam = src[2];
  float c = cosf(0.5f * th), s = sinf(0.5f * th);
  float cl = cosf(lam), sl = sinf(lam);
  float cp = cosf(ph), spv = sinf(ph);
  float cpl = cosf(ph + lam), spl = sinf(ph + lam);
  o[0] = c;        o[1] = 0.0f;
  o[2] = -cl * s;  o[3] = -sl * s;
  o[4] = cp * s;   o[5] = spv * s;
  o[6] = cpl * c;  o[7] = spl * c;
}

// ---------------------------------------------------------------------------
// Conv (blocks 0..511) + fused-gate/FC prep (block 512).
// G layout (640 floats):
//   [0..7]           F0 = U[0][0]
//   per b: 8+b*112 : F1..F5 (k=0..4): {M0=U[b][k+1], M1=C[b][k]*U[b][k+1]} x16
//                    +80: F6 {U[b][6], C[b][5]*U[b][6]}
//                    +96: F7 {U[b][7], C[b][6]*U[b][7]}
//   568+b*16 (b<4) : F8' {M0=U[b+1][0], M1=U[b+1][0]*C[b][7]}
//   632            : F8 = C[4][7]
// ---------------------------------------------------------------------------
__global__ __launch_bounds__(256) void conv_prep_kernel(
    const float* __restrict__ x, const float* __restrict__ cw,
    const float* __restrict__ cb, const float* __restrict__ u3p,
    const float* __restrict__ cu3p, const float* __restrict__ fcw,
    const float* __restrict__ fcb, float* __restrict__ ang,
    float* __restrict__ G, float* __restrict__ FCW, float* __restrict__ FCB) {
  if (blockIdx.x == 512) {
    __shared__ float Us[40][8];
    __shared__ float Cs[40][8];
    int t = threadIdx.x;
    if (t < 40) u3fill(u3p + t * 3, Us[t]);
    if (t >= 64 && t < 104) u3fill(cu3p + (t - 64) * 3, Cs[t - 64]);
    __syncthreads();
    if (t == 0) {
#pragma unroll
      for (int j = 0; j < 8; ++j) G[j] = Us[0][j];
    } else if (t < 36) {
      int j = t - 1, b = j / 7, k = j % 7;
      float* dst = G + 8 + b * 112 + k * 16;
      const float* U = Us[b * 8 + k + 1];
      const float* C = Cs[b * 8 + k];
#pragma unroll
      for (int q = 0; q < 8; ++q) dst[q] = U[q];
      mm2(C, U, dst + 8);
    } else if (t < 40) {
      int b = t - 36;
      float* dst = G + 568 + b * 16;
      const float* U = Us[(b + 1) * 8];
      const float* C = Cs[b * 8 + 7];
#pragma unroll
      for (int q = 0; q < 8; ++q) dst[q] = U[q];
      mm2(U, C, dst + 8);
    } else if (t == 40) {
#pragma unroll
      for (int j = 0; j < 8; ++j) G[632 + j] = Cs[39][j];
    }
    for (int i = t; i < 768; i += 256) {
      int col = i % 24;
      float sc = col < 8 ? 1.0f : (col < 16 ? (1.0f/256.0f) : (1.0f/65536.0f));
      FCW[i] = fcw[i] * sc;
    }
    if (t < 32) FCB[t] = fcb[t];
    return;
  }
  int tid = blockIdx.x * blockDim.x + threadIdx.x;
  int oc = tid >> 14;
  int p  = tid & (N_PIX - 1);
  int b  = p >> 12;
  int h  = (p >> 6) & 63;
  int w  = p & 63;
  float acc = cb[oc];
  for (int ic = 0; ic < 16; ++ic) {
    const float* xp = x + ((b * 16 + ic) * 64) * 64;
    const float* wp = cw + (oc * 16 + ic) * 9;
#pragma unroll
    for (int kh = 0; kh < 3; ++kh) {
      int ih = h + kh - 1;
      if ((unsigned)ih < 64u) {
#pragma unroll
        for (int kw = 0; kw < 3; ++kw) {
          int iw = w + kw - 1;
          if ((unsigned)iw < 64u)
            acc = fmaf(xp[ih * 64 + iw], wp[kh * 3 + kw], acc);
        }
      }
    }
  }
  ang[oc * N_PIX + p] = acc;
}

// ---------------------------------------------------------------------------
// Quantum simulator: 2 pixels per wave64, packed fp32 (v_pk_fma_f32).
// ---------------------------------------------------------------------------
__global__ __launch_bounds__(256) void qsim_kernel(
    const float* __restrict__ ang, const float* __restrict__ G,
    const float* __restrict__ FCW, const float* __restrict__ FCB,
    float* __restrict__ out) {
  const int lane = threadIdx.x & 63;
  const int a32 = ((lane ^ 32) << 2);
  const int wid = __builtin_amdgcn_readfirstlane(
      (int)((blockIdx.x * blockDim.x + threadIdx.x) >> 6));
  const int p0 = wid * 2, p1 = p0 + 1;

  float sgv[6];
#pragma unroll
  for (int k = 0; k < 6; ++k) sgv[k] = (lane & (1 << k)) ? -1.0f : 1.0f;

  float cA[8], sA[8], cB[8], sB[8];
#pragma unroll
  for (int w = 0; w < 8; ++w) {
    float aa = 0.5f * ang[w * N_PIX + p0];
    float ab = 0.5f * ang[w * N_PIX + p1];
    __sincosf(aa, &sA[w], &cA[w]);
    __sincosf(ab, &sB[w], &cB[w]);
  }
  v2f Sr[4], Si[4];
  {
    float fA = ((lane & 32) ? sA[0] : cA[0]) * ((lane & 16) ? sA[1] : cA[1]);
    fA *= ((lane & 8) ? sA[2] : cA[2]);
    fA *= ((lane & 4) ? sA[3] : cA[3]);
    fA *= ((lane & 2) ? sA[4] : cA[4]);
    fA *= ((lane & 1) ? sA[5] : cA[5]);
    float fB = ((lane & 32) ? sB[0] : cB[0]) * ((lane & 16) ? sB[1] : cB[1]);
    fB *= ((lane & 8) ? sB[2] : cB[2]);
    fB *= ((lane & 4) ? sB[3] : cB[3]);
    fB *= ((lane & 2) ? sB[4] : cB[4]);
    fB *= ((lane & 1) ? sB[5] : cB[5]);
    Sr[0].x = fA * (cA[6]*cA[7]); Sr[0].y = fB * (cB[6]*cB[7]);
    Sr[1].x = fA * (cA[6]*sA[7]); Sr[1].y = fB * (cB[6]*sB[7]);
    Sr[2].x = fA * (sA[6]*cA[7]); Sr[2].y = fB * (sB[6]*cB[7]);
    Sr[3].x = fA * (sA[6]*sA[7]); Sr[3].y = fB * (sB[6]*sB[7]);
    Si[0] = sp(0.0f); Si[1] = sp(0.0f); Si[2] = sp(0.0f); Si[3] = sp(0.0f);
  }

  // Fused circuit: F0, then per block F1..F7 (+F8' into next block), F8 last.
  crossg<32, 0>(Sr, Si, G, lane, a32);
  for (int b = 0; b < 5; ++b) {
    const float* base = G + 8 + b * 112;
    crossg<16, 32>(Sr, Si, base +  0, lane, a32);
    crossg<8, 16> (Sr, Si, base + 16, lane, a32);
    crossg<4, 8>  (Sr, Si, base + 32, lane, a32);
    crossg<2, 4>  (Sr, Si, base + 48, lane, a32);
    crossg<1, 2>  (Sr, Si, base + 64, lane, a32);
    f6(Sr, Si, base + 80, lane);
    f7(Sr, Si, base + 96);
    if (b < 4) f8p(Sr, Si, G + 568 + b * 16, lane, a32);
  }
  f8(Sr, Si, G + 632, lane, a32);

  float mzA[8], mzB[8], mxA[8], mxB[8], myA[8], myB[8];
  measureP(Sr, Si, lane, a32, sgv, mzA, mzB);
  hstepP<1>(Sr, Si, sp(sgv[0]), a32);
  hstepP<2>(Sr, Si, sp(sgv[1]), a32);
  hstepP<4>(Sr, Si, sp(sgv[2]), a32);
  hstepP<8>(Sr, Si, sp(sgv[3]), a32);
  hstepP<16>(Sr, Si, sp(sgv[4]), a32);
  hstepP<32>(Sr, Si, sp(sgv[5]), a32);
  h_intraP(Sr, Si);
  measureP(Sr, Si, lane, a32, sgv, mxA, mxB);
  phaseY(Sr, Si, lane);
  hstepP<1>(Sr, Si, sp(sgv[0]), a32);
  hstepP<2>(Sr, Si, sp(sgv[1]), a32);
  hstepP<4>(Sr, Si, sp(sgv[2]), a32);
  hstepP<8>(Sr, Si, sp(sgv[3]), a32);
  hstepP<16>(Sr, Si, sp(sgv[4]), a32);
  hstepP<32>(Sr, Si, sp(sgv[5]), a32);
  h_intraP(Sr, Si);
  measureP(Sr, Si, lane, a32, sgv, myA, myB);

  // FC: lanes 0-31 -> pixel p0 channel lane; lanes 32-63 -> pixel p1.
  const bool selA = lane < 32;
  const int c = lane & 31;
  float wv[24];
  const float4* w4 = reinterpret_cast<const float4*>(FCW + c * 24);
#pragma unroll
  for (int q = 0; q < 6; ++q) {
    float4 t = w4[q];
    wv[q*4+0] = t.x; wv[q*4+1] = t.y; wv[q*4+2] = t.z; wv[q*4+3] = t.w;
  }
  float acc = FCB[c];
#pragma unroll
  for (int j = 0; j < 8; ++j) acc = fmaf(selA ? mzA[j] : mzB[j], wv[j], acc);
#pragma unroll
  for (int j = 0; j < 8; ++j) acc = fmaf(selA ? mxA[j] : mxB[j], wv[8 + j], acc);
#pragma unroll
  for (int j = 0; j < 8; ++j) acc = fmaf(selA ? myA[j] : myB[j], wv[16 + j], acc);
  int p = selA ? p0 : p1;
  out[(p >> 12) * 131072 + c * 4096 + (p & 4095)] = acc;
}

extern "C" void kernel_launch(void* const* d_in, const int* in_sizes, int n_in,
                              void* d_out, int out_size, void* d_ws, size_t ws_size,
                              hipStream_t stream) {
  const float* x      = (const float*)d_in[0];
  const float* conv_w = (const float*)d_in[1];
  const float* conv_b = (const float*)d_in[2];
  const float* u3p    = (const float*)d_in[3];
  const float* cu3p   = (const float*)d_in[4];
  const float* fcw    = (const float*)d_in[5];
  const float* fcb    = (const float*)d_in[6];
  float* out = (float*)d_out;

  float* ws  = (float*)d_ws;
  float* ang = ws;               // 8 * 16384
  float* G   = ws + 8 * N_PIX;   // 640 (fused gate matrices)
  float* FCW = G + 640;          // 768 (pre-scaled: cols 8-15 /256, 16-23 /65536)
  float* FCB = FCW + 768;        // 32

  conv_prep_kernel<<<513, 256, 0, stream>>>(x, conv_w, conv_b, u3p, cu3p,
                                            fcw, fcb, ang, G, FCW, FCB);
  qsim_kernel<<<2048, 256, 0, stream>>>(ang, G, FCW, FCB, out);
}